// Round 13
// baseline (704.096 us; speedup 1.0000x reference)
//
#include <hip/hip_runtime.h>
#include <hip/hip_bf16.h>

#define N_NODES 50000
#define N_EDGES 800000

typedef __bf16 bf16x8 __attribute__((ext_vector_type(8)));
typedef float f32x4 __attribute__((ext_vector_type(4)));

__device__ __forceinline__ float loadF(const void* p, size_t i, bool isbf) {
    return isbf ? __bfloat162float(((const __hip_bfloat16*)p)[i]) : ((const float*)p)[i];
}
__device__ __forceinline__ float bfbits2f(unsigned short u) {
    return __uint_as_float(((unsigned)u) << 16);
}
__device__ __forceinline__ unsigned short f2bfbits(float f) {
    __hip_bfloat16 h = __float2bfloat16(f);
    return *(unsigned short*)&h;
}

// ---------- convert + zero-init (with built-in per-block dtype detect) ----------
__global__ void cvt_all_k(const void* __restrict__ x, const void* __restrict__ W1,
                          const void* __restrict__ W2, const void* __restrict__ Wo,
                          unsigned short* __restrict__ Xb, unsigned short* __restrict__ W1f,
                          unsigned short* __restrict__ W2f, unsigned short* __restrict__ Wof,
                          int* __restrict__ flag, uint4* __restrict__ zbase, int nzu) {
    __shared__ int s_flag;
    int t = threadIdx.x;
    if (t < 64) {
        const unsigned short* xw = (const unsigned short*)x;
        int cnt = 0;
        for (int i = t; i < 512; i += 64) {
            unsigned e = (xw[2 * i] >> 7) & 0xFFu;
            if (e >= 117u && e <= 134u) cnt++;
        }
        for (int off = 32; off; off >>= 1) cnt += __shfl_down(cnt, off, 64);
        if (t == 0) s_flag = (cnt >= 256) ? 1 : 0;
    }
    __syncthreads();
    bool bf = (s_flag != 0);
    int i = blockIdx.x * blockDim.x + t;
    if (i == 0) *flag = s_flag ? 1 : 0;
    if (i < 800000) {
        if (bf) {
            ((uint4*)Xb)[i] = ((const uint4*)x)[i];
        } else {
            const float* f = (const float*)x + (size_t)i * 8;
            unsigned short r[8];
            for (int j = 0; j < 8; ++j) r[j] = f2bfbits(f[j]);
            *(uint4*)(Xb + (size_t)i * 8) = *(uint4*)r;
        }
        return;
    }
    int u = i - 800000;
    const void* W; unsigned short* dst; int Nf, Npad, s, rem;
    if (u < 4096)        { W = W1; dst = W1f; Nf = 256; Npad = 256; s = u / 1024; rem = u % 1024; }
    else if (u < 12288)  { u -= 4096;  W = W2; dst = W2f; Nf = 256; Npad = 256; s = u / 1024; rem = u % 1024; }
    else if (u < 14336)  { u -= 12288; W = Wo; dst = Wof; Nf = 40;  Npad = 64;  s = u / 256;  rem = u % 256; }
    else {
        int z = u - 14336;
        if (z < nzu) zbase[z] = make_uint4(0u, 0u, 0u, 0u);
        return;
    }
    int n = rem >> 2, quad = rem & 3;
    unsigned short r[8];
    for (int j = 0; j < 8; ++j) {
        int k = s * 32 + quad * 8 + j;
        r[j] = (n < Nf) ? f2bfbits(loadF(W, (size_t)k * Nf + n, bf)) : (unsigned short)0;
    }
    int uo = (s * Npad + n) * 4 + quad;
    *(uint4*)(dst + (size_t)uo * 8) = *(uint4*)r;
}

// ---------- fused CSR build: hist -> scan1 -> scan23 -> scatter, one kernel ----------
// 1024 blocks x 256 threads = 4 blocks/CU (16 waves/CU) -> co-resident
// (VGPR 8, LDS 1.5KB: far below the 8-block/CU capacity), so the grid
// barrier cannot deadlock while phases 0/3 run at decent occupancy.
__device__ __forceinline__ void gbar(int* bar, int phase, int nb) {
    __syncthreads();
    if (threadIdx.x == 0) {
        __threadfence();
        atomicAdd(bar, 1);
        int target = (phase + 1) * nb;
        while (atomicAdd(bar, 0) < target) __builtin_amdgcn_s_sleep(2);
        __threadfence();
    }
    __syncthreads();
}

__global__ __launch_bounds__(256)
void csr_fused_k(const int* __restrict__ src, const int* __restrict__ dst,
                 int* __restrict__ cursor, int* __restrict__ rowptr,
                 int* __restrict__ bsum, int* __restrict__ ecol,
                 int* __restrict__ bar, int N, int E) {
    int nb = gridDim.x;
    int t = threadIdx.x, b = blockIdx.x;
    int gid = b * 256 + t;
    int gsz = nb * 256;
    int NB = (N + 255) / 256;

    // phase 0: histogram of dst into cursor
    for (int e = gid; e < E; e += gsz) atomicAdd(&cursor[dst[e]], 1);
    gbar(bar, 0, nb);

    // phase 1: block-local exclusive scan (blocks 0..NB-1)
    if (b < NB) {
        __shared__ int s[256];
        int g = b * 256 + t;
        int v = (g < N) ? cursor[g] : 0;
        s[t] = v; __syncthreads();
        for (int off = 1; off < 256; off <<= 1) {
            int x = (t >= off) ? s[t - off] : 0;
            __syncthreads();
            s[t] += x;
            __syncthreads();
        }
        if (g < N) rowptr[g] = s[t] - v;
        if (t == 255) bsum[b] = s[255];
    }
    gbar(bar, 1, nb);

    // phase 2: add block-prefix offsets (blocks 0..NB-1)
    if (b < NB) {
        __shared__ int ws[4];
        __shared__ int s_off;
        int wave = t >> 6, lane = t & 63;
        int v = (t < b && t < 256) ? bsum[t] : 0;   // NB <= 256
        for (int off = 32; off; off >>= 1) v += __shfl_down(v, off, 64);
        if (lane == 0) ws[wave] = v;
        __syncthreads();
        if (t == 0) s_off = ws[0] + ws[1] + ws[2] + ws[3];
        __syncthreads();
        int g = b * 256 + t;
        if (g < N) rowptr[g] += s_off;
        if (g == 0) rowptr[N] = E;
    }
    gbar(bar, 2, nb);

    // phase 3: scatter src ids into CSR slots (cursor = remaining count)
    for (int e = gid; e < E; e += gsz) {
        int d = dst[e];
        int r = atomicSub(&cursor[d], 1);
        ecol[rowptr[d] + r - 1] = src[e];
    }
}

// ---------- LDS-free MFMA GEMM + fused attention coefficients ----------
template <int K_, int AMODE>
__global__ __launch_bounds__(256)
void gemm_attn_k(const unsigned short* __restrict__ A, const unsigned short* __restrict__ Wf,
                 __hip_bfloat16* __restrict__ C, const void* __restrict__ al,
                 const void* __restrict__ ar, const int* __restrict__ flag,
                 float* __restrict__ el, float* __restrict__ er, int M, int Nfull, int Npad) {
    int t = threadIdx.x;
    int row0 = blockIdx.x * 128, col0 = blockIdx.y * 64;
    int wave = t >> 6, lane = t & 63;
    int wr = (wave >> 1) * 64, wc = (wave & 1) * 32;
    int m16 = lane & 15, quad = lane >> 4;

    const unsigned short* arow[4];
    for (int mt = 0; mt < 4; ++mt) {
        int gr = row0 + wr + mt * 16 + m16;
        int grc = (gr < M) ? gr : (M - 1);
        arow[mt] = A + (size_t)grc * K_ + quad * 8;
    }
    const unsigned short* bbase[2];
    for (int nt = 0; nt < 2; ++nt) {
        int gc = col0 + wc + nt * 16 + m16;
        bbase[nt] = Wf + ((size_t)(gc * 4 + quad) << 3);
    }

    f32x4 acc[4][2] = {};
#pragma unroll
    for (int s = 0; s < K_ / 32; ++s) {
        bf16x8 a[4], b[2];
        for (int mt = 0; mt < 4; ++mt)
            a[mt] = *(const bf16x8*)(arow[mt] + s * 32);
        for (int nt = 0; nt < 2; ++nt)
            b[nt] = *(const bf16x8*)(bbase[nt] + (size_t)s * Npad * 32);
        for (int mt = 0; mt < 4; ++mt)
            for (int nt = 0; nt < 2; ++nt)
                acc[mt][nt] = __builtin_amdgcn_mfma_f32_16x16x32_bf16(
                    a[mt], b[nt], acc[mt][nt], 0, 0, 0);
    }

    int cld = (AMODE == 0) ? Nfull : Npad;
    for (int mt = 0; mt < 4; ++mt)
        for (int nt = 0; nt < 2; ++nt)
            for (int r = 0; r < 4; ++r) {
                int gr = row0 + wr + mt * 16 + quad * 4 + r;
                int gc = col0 + wc + nt * 16 + m16;
                if (gr < M && gc < cld)
                    C[(size_t)gr * cld + gc] = __float2bfloat16(acc[mt][nt][r]);
            }

    bool bf = (*flag != 0);
    float alc[2], arc[2];
    for (int nt = 0; nt < 2; ++nt) {
        int gc = col0 + wc + nt * 16 + m16;
        bool ok = gc < Nfull;
        alc[nt] = ok ? loadF(al, gc, bf) : 0.f;
        arc[nt] = ok ? loadF(ar, gc, bf) : 0.f;
    }
    for (int mt = 0; mt < 4; ++mt)
        for (int r = 0; r < 4; ++r) {
            float pl = acc[mt][0][r] * alc[0] + acc[mt][1][r] * alc[1];
            float pr = acc[mt][0][r] * arc[0] + acc[mt][1][r] * arc[1];
            for (int off = 1; off < 16; off <<= 1) {
                pl += __shfl_xor(pl, off, 64);
                pr += __shfl_xor(pr, off, 64);
            }
            if (m16 == 0) {
                int gr = row0 + wr + mt * 16 + quad * 4 + r;
                if (gr < M) {
                    if (AMODE == 0) {
                        int hd = col0 / 32 + (wave & 1);
                        el[gr * 8 + hd] = pl;
                        er[gr * 8 + hd] = pr;
                    } else {
                        atomicAdd(&el[gr], pl);
                        atomicAdd(&er[gr], pr);
                    }
                }
            }
        }
}

// ---------- single-pass half-wave aggregation (H=8, F=32), unrolled x4 ----------
__global__ __launch_bounds__(256)
void aggr1_k(const int* __restrict__ rowptr, const int* __restrict__ ecol,
             const float* __restrict__ el, const float* __restrict__ er,
             const __hip_bfloat16* __restrict__ Hp, __hip_bfloat16* __restrict__ out, int N) {
    int t = threadIdx.x;
    int hw = t >> 5, l = t & 31;
    int n = blockIdx.x * 8 + hw;
    if (n >= N) return;
    int beg = rowptr[n], deg = rowptr[n + 1] - beg;

    int hh = l >> 2;
    float er_hh = er[n * 8 + hh];
    float ss = 0.f;
    float acc[8] = {0.f, 0.f, 0.f, 0.f, 0.f, 0.f, 0.f, 0.f};
    const unsigned short* hp = (const unsigned short*)Hp;

    int i = 0;
    for (; i + 4 <= deg; i += 4) {
        int s0 = ecol[beg + i], s1 = ecol[beg + i + 1];
        int s2 = ecol[beg + i + 2], s3 = ecol[beg + i + 3];
        uint4 r0 = *(const uint4*)(hp + (size_t)s0 * 256 + l * 8);
        uint4 r1 = *(const uint4*)(hp + (size_t)s1 * 256 + l * 8);
        uint4 r2 = *(const uint4*)(hp + (size_t)s2 * 256 + l * 8);
        uint4 r3 = *(const uint4*)(hp + (size_t)s3 * 256 + l * 8);
        float v0 = el[s0 * 8 + hh] + er_hh;
        float v1 = el[s1 * 8 + hh] + er_hh;
        float v2 = el[s2 * 8 + hh] + er_hh;
        float v3 = el[s3 * 8 + hh] + er_hh;
        v0 = (v0 >= 0.f) ? v0 : 0.2f * v0;
        v1 = (v1 >= 0.f) ? v1 : 0.2f * v1;
        v2 = (v2 >= 0.f) ? v2 : 0.2f * v2;
        v3 = (v3 >= 0.f) ? v3 : 0.2f * v3;
        float e0 = __expf(v0), e1 = __expf(v1), e2 = __expf(v2), e3 = __expf(v3);
        ss += (e0 + e1) + (e2 + e3);
        unsigned short u0[8], u1[8], u2[8], u3[8];
        *(uint4*)u0 = r0;
        *(uint4*)u1 = r1;
        *(uint4*)u2 = r2;
        *(uint4*)u3 = r3;
        for (int j = 0; j < 8; ++j)
            acc[j] += (e0 * bfbits2f(u0[j]) + e1 * bfbits2f(u1[j])) +
                      (e2 * bfbits2f(u2[j]) + e3 * bfbits2f(u3[j]));
    }
    for (; i < deg; ++i) {
        int s0 = ecol[beg + i];
        uint4 r0 = *(const uint4*)(hp + (size_t)s0 * 256 + l * 8);
        float v0 = el[s0 * 8 + hh] + er_hh;
        v0 = (v0 >= 0.f) ? v0 : 0.2f * v0;
        float e0 = __expf(v0);
        ss += e0;
        unsigned short u0[8];
        *(uint4*)u0 = r0;
        for (int j = 0; j < 8; ++j) acc[j] += e0 * bfbits2f(u0[j]);
    }

    float inv = 1.f / (ss + 1e-16f);
    unsigned short o[8];
    for (int j = 0; j < 8; ++j) {
        float vv = acc[j] * inv;
        vv = (vv > 0.f) ? vv : expm1f(vv);   // ELU
        o[j] = f2bfbits(vv);
    }
    *(uint4*)((unsigned short*)out + (size_t)n * 256 + l * 8) = *(uint4*)o;
}

// ---------- output layer: 8-way vectorized aggregation (stride-64 Hp) + log_softmax ----------
__global__ __launch_bounds__(64)
void aggr_out_k(const int* __restrict__ rowptr, const int* __restrict__ ecol,
                const float* __restrict__ elo, const float* __restrict__ ero,
                const unsigned short* __restrict__ Hp64, void* __restrict__ outp,
                const int* __restrict__ flag, int N) {
    int n = blockIdx.x, l = threadIdx.x;
    int g = l >> 3, f = l & 7;
    int beg = rowptr[n], deg = rowptr[n + 1] - beg;
    float ero_n = ero[n];
    float ss = 0.f;
    float acc[8] = {0.f, 0.f, 0.f, 0.f, 0.f, 0.f, 0.f, 0.f};
    for (int i = g; i < deg; i += 8) {
        int s = ecol[beg + i];
        float v = elo[s] + ero_n;
        v = (v >= 0.f) ? v : 0.2f * v;
        float ex = __expf(v);
        ss += ex;
        uint4 r = *(const uint4*)(Hp64 + (size_t)s * 64 + f * 8);
        unsigned short u[8];
        *(uint4*)u = r;
        for (int j = 0; j < 8; ++j) acc[j] += ex * bfbits2f(u[j]);
    }
    for (int off = 8; off <= 32; off <<= 1) {
        ss += __shfl_xor(ss, off, 64);
        for (int j = 0; j < 8; ++j) acc[j] += __shfl_xor(acc[j], off, 64);
    }
    float inv = 1.f / (ss + 1e-16f);
    float r8[8];
    float vmax = -1e30f;
    for (int j = 0; j < 8; ++j) {
        r8[j] = acc[j] * inv;
        if (f < 5) vmax = fmaxf(vmax, r8[j]);
    }
    for (int off = 1; off <= 4; off <<= 1) vmax = fmaxf(vmax, __shfl_xor(vmax, off, 64));
    float es = 0.f;
    if (f < 5)
        for (int j = 0; j < 8; ++j) es += __expf(r8[j] - vmax);
    for (int off = 1; off <= 4; off <<= 1) es += __shfl_xor(es, off, 64);
    float lse = vmax + logf(es);
    if (f < 5 && g == 0) {
        if (*flag) {
            unsigned short o[8];
            for (int j = 0; j < 8; ++j) o[j] = f2bfbits(r8[j] - lse);
            *(uint4*)((unsigned short*)outp + (size_t)n * 40 + f * 8) = *(uint4*)o;
        } else {
            float* fo = (float*)outp + (size_t)n * 40 + f * 8;
            for (int j = 0; j < 8; ++j) fo[j] = r8[j] - lse;
        }
    }
}

extern "C" void kernel_launch(void* const* d_in, const int* in_sizes, int n_in,
                              void* d_out, int out_size, void* d_ws, size_t ws_size,
                              hipStream_t stream) {
    const int N = N_NODES, E = N_EDGES;
    const void* x   = d_in[0];
    const int* src  = (const int*)d_in[1];
    const int* dst  = (const int*)d_in[2];
    const void* W1  = d_in[3];
    const void* al1 = d_in[4];
    const void* ar1 = d_in[5];
    const void* W2  = d_in[6];
    const void* al2 = d_in[7];
    const void* ar2 = d_in[8];
    const void* Wo  = d_in[9];
    const void* alo = d_in[10];
    const void* aro = d_in[11];

    // workspace (~58.6 MB); cursor|elo|ero|bar contiguous (zeroed by cvt_all)
    char* w = (char*)d_ws;
    auto alloc = [&](size_t bytes) { void* p = (void*)w; w += (bytes + 255) & ~(size_t)255; return p; };
    int* flag      = (int*)alloc(4);
    int* rowptr    = (int*)alloc((size_t)(N + 1) * 4);
    int* cursor    = (int*)alloc((size_t)N * 4);   // padded to 200192 B
    float* elo     = (float*)alloc((size_t)N * 4); // padded to 200192 B
    float* ero     = (float*)alloc((size_t)N * 4); // padded to 200192 B
    int* bar       = (int*)alloc(256);             // barrier counter
    int* bsum      = (int*)alloc(256 * 4);
    int* ecol      = (int*)alloc((size_t)E * 4);
    float* el      = (float*)alloc((size_t)N * 8 * 4);
    float* er      = (float*)alloc((size_t)N * 8 * 4);
    unsigned short* W1f = (unsigned short*)alloc((size_t)128 * 256 * 2);
    unsigned short* W2f = (unsigned short*)alloc((size_t)256 * 256 * 2);
    unsigned short* Wof = (unsigned short*)alloc((size_t)256 * 64 * 2);
    __hip_bfloat16* Hp   = (__hip_bfloat16*)alloc((size_t)N * 256 * 2);
    __hip_bfloat16* Hagg = (__hip_bfloat16*)alloc((size_t)N * 256 * 2);
    unsigned short* Xb = (unsigned short*)Hagg;   // alias: dead after layer-1 gemm

    // zero span: cursor..bar inclusive = 3*200192 + 256 bytes = 600832 B = 37552 uint4
    const int NZU = 37552;

    int MB = (N + 127) / 128;
    int AB = (N + 7) / 8;
    int CVT_THREADS = 800000 + 14336 + NZU;

    cvt_all_k<<<(CVT_THREADS + 255) / 256, 256, 0, stream>>>(
        x, W1, W2, Wo, Xb, W1f, W2f, Wof, flag, (uint4*)cursor, NZU);
    csr_fused_k<<<1024, 256, 0, stream>>>(src, dst, cursor, rowptr, bsum, ecol, bar, N, E);

    // layer 1
    gemm_attn_k<128, 0><<<dim3(MB, 4), 256, 0, stream>>>(Xb, W1f, Hp, al1, ar1, flag, el, er, N, 256, 256);
    aggr1_k<<<AB, 256, 0, stream>>>(rowptr, ecol, el, er, Hp, Hagg, N);

    // layer 2
    gemm_attn_k<256, 0><<<dim3(MB, 4), 256, 0, stream>>>((const unsigned short*)Hagg, W2f, Hp, al2, ar2, flag, el, er, N, 256, 256);
    aggr1_k<<<AB, 256, 0, stream>>>(rowptr, ecol, el, er, Hp, Hagg, N);

    // output layer (C stored with stride 64, zero-padded cols 40..63)
    gemm_attn_k<256, 1><<<dim3(MB, 1), 256, 0, stream>>>((const unsigned short*)Hagg, Wof, Hp, alo, aro, flag, elo, ero, N, 40, 64);
    aggr_out_k<<<N, 64, 0, stream>>>(rowptr, ecol, elo, ero, (const unsigned short*)Hp, d_out, flag, N);
}

// Round 14
// 441.447 us; speedup vs baseline: 1.5950x; 1.5950x over previous
//
#include <hip/hip_runtime.h>
#include <hip/hip_bf16.h>

#define N_NODES 50000
#define N_EDGES 800000

typedef __bf16 bf16x8 __attribute__((ext_vector_type(8)));
typedef float f32x4 __attribute__((ext_vector_type(4)));

__device__ __forceinline__ float loadF(const void* p, size_t i, bool isbf) {
    return isbf ? __bfloat162float(((const __hip_bfloat16*)p)[i]) : ((const float*)p)[i];
}
__device__ __forceinline__ float bfbits2f(unsigned short u) {
    return __uint_as_float(((unsigned)u) << 16);
}
__device__ __forceinline__ unsigned short f2bfbits(float f) {
    __hip_bfloat16 h = __float2bfloat16(f);
    return *(unsigned short*)&h;
}

// ---------- convert + histogram (independent work fused; per-block dtype detect) ----------
// ranges: [0,800000) x-cvt | [800000,814336) W-swizzle | [814336,1614336) dst-hist
__global__ void cvt_hist_k(const void* __restrict__ x, const void* __restrict__ W1,
                           const void* __restrict__ W2, const void* __restrict__ Wo,
                           unsigned short* __restrict__ Xb, unsigned short* __restrict__ W1f,
                           unsigned short* __restrict__ W2f, unsigned short* __restrict__ Wof,
                           int* __restrict__ flag, const int* __restrict__ dst,
                           int* __restrict__ cursor) {
    __shared__ int s_flag;
    int t = threadIdx.x;
    if (t < 64) {
        const unsigned short* xw = (const unsigned short*)x;
        int cnt = 0;
        for (int i = t; i < 512; i += 64) {
            unsigned e = (xw[2 * i] >> 7) & 0xFFu;
            if (e >= 117u && e <= 134u) cnt++;
        }
        for (int off = 32; off; off >>= 1) cnt += __shfl_down(cnt, off, 64);
        if (t == 0) s_flag = (cnt >= 256) ? 1 : 0;
    }
    __syncthreads();
    bool bf = (s_flag != 0);
    int i = blockIdx.x * blockDim.x + t;
    if (i == 0) *flag = s_flag ? 1 : 0;
    if (i < 800000) {
        if (bf) {
            ((uint4*)Xb)[i] = ((const uint4*)x)[i];
        } else {
            const float* f = (const float*)x + (size_t)i * 8;
            unsigned short r[8];
            for (int j = 0; j < 8; ++j) r[j] = f2bfbits(f[j]);
            *(uint4*)(Xb + (size_t)i * 8) = *(uint4*)r;
        }
        return;
    }
    int u = i - 800000;
    if (u >= 14336) {
        int e = u - 14336;
        if (e < N_EDGES) atomicAdd(&cursor[dst[e]], 1);
        return;
    }
    const void* W; unsigned short* dstp; int Nf, Npad, s, rem;
    if (u < 4096)        { W = W1; dstp = W1f; Nf = 256; Npad = 256; s = u / 1024; rem = u % 1024; }
    else if (u < 12288)  { u -= 4096;  W = W2; dstp = W2f; Nf = 256; Npad = 256; s = u / 1024; rem = u % 1024; }
    else                 { u -= 12288; W = Wo; dstp = Wof; Nf = 40;  Npad = 64;  s = u / 256;  rem = u % 256; }
    int n = rem >> 2, quad = rem & 3;
    unsigned short r[8];
    for (int j = 0; j < 8; ++j) {
        int k = s * 32 + quad * 8 + j;
        r[j] = (n < Nf) ? f2bfbits(loadF(W, (size_t)k * Nf + n, bf)) : (unsigned short)0;
    }
    int uo = (s * Npad + n) * 4 + quad;
    *(uint4*)(dstp + (size_t)uo * 8) = *(uint4*)r;
}

// ---------- sync-free full scan: each block independently sums its prefix ----------
__global__ __launch_bounds__(256)
void scanall_k(const int* __restrict__ deg, int* __restrict__ rowptr, int N, int E) {
    __shared__ int s[256];
    __shared__ int ws[4];
    __shared__ int s_off;
    int t = threadIdx.x, b = blockIdx.x;
    int base = b * 256;
    // prefix sum of deg[0..base): coalesced strided accumulate + block reduce
    int acc = 0;
    for (int i = t; i < base; i += 256) acc += deg[i];
    int wave = t >> 6, lane = t & 63;
    for (int off = 32; off; off >>= 1) acc += __shfl_down(acc, off, 64);
    if (lane == 0) ws[wave] = acc;
    __syncthreads();
    if (t == 0) s_off = ws[0] + ws[1] + ws[2] + ws[3];
    __syncthreads();
    // local exclusive scan of this block's 256 entries
    int g = base + t;
    int v = (g < N) ? deg[g] : 0;
    s[t] = v; __syncthreads();
    for (int off = 1; off < 256; off <<= 1) {
        int x = (t >= off) ? s[t - off] : 0;
        __syncthreads();
        s[t] += x;
        __syncthreads();
    }
    if (g < N) rowptr[g] = s_off + s[t] - v;
    if (b == 0 && t == 0) rowptr[N] = E;
}

// ---------- LDS-free MFMA GEMM + fused attention coefficients (device body) ----------
template <int K_, int AMODE>
__device__ __forceinline__
void gemm_attn_body(int bx, int by, int t,
                    const unsigned short* __restrict__ A, const unsigned short* __restrict__ Wf,
                    __hip_bfloat16* __restrict__ C, const void* __restrict__ al,
                    const void* __restrict__ ar, const int* __restrict__ flag,
                    float* __restrict__ el, float* __restrict__ er, int M, int Nfull, int Npad) {
    int row0 = bx * 128, col0 = by * 64;
    int wave = t >> 6, lane = t & 63;
    int wr = (wave >> 1) * 64, wc = (wave & 1) * 32;
    int m16 = lane & 15, quad = lane >> 4;

    const unsigned short* arow[4];
    for (int mt = 0; mt < 4; ++mt) {
        int gr = row0 + wr + mt * 16 + m16;
        int grc = (gr < M) ? gr : (M - 1);
        arow[mt] = A + (size_t)grc * K_ + quad * 8;
    }
    const unsigned short* bbase[2];
    for (int nt = 0; nt < 2; ++nt) {
        int gc = col0 + wc + nt * 16 + m16;
        bbase[nt] = Wf + ((size_t)(gc * 4 + quad) << 3);
    }

    f32x4 acc[4][2] = {};
#pragma unroll
    for (int s = 0; s < K_ / 32; ++s) {
        bf16x8 a[4], b[2];
        for (int mt = 0; mt < 4; ++mt)
            a[mt] = *(const bf16x8*)(arow[mt] + s * 32);
        for (int nt = 0; nt < 2; ++nt)
            b[nt] = *(const bf16x8*)(bbase[nt] + (size_t)s * Npad * 32);
        for (int mt = 0; mt < 4; ++mt)
            for (int nt = 0; nt < 2; ++nt)
                acc[mt][nt] = __builtin_amdgcn_mfma_f32_16x16x32_bf16(
                    a[mt], b[nt], acc[mt][nt], 0, 0, 0);
    }

    int cld = (AMODE == 0) ? Nfull : Npad;
    for (int mt = 0; mt < 4; ++mt)
        for (int nt = 0; nt < 2; ++nt)
            for (int r = 0; r < 4; ++r) {
                int gr = row0 + wr + mt * 16 + quad * 4 + r;
                int gc = col0 + wc + nt * 16 + m16;
                if (gr < M && gc < cld)
                    C[(size_t)gr * cld + gc] = __float2bfloat16(acc[mt][nt][r]);
            }

    bool bf = (*flag != 0);
    float alc[2], arc[2];
    for (int nt = 0; nt < 2; ++nt) {
        int gc = col0 + wc + nt * 16 + m16;
        bool ok = gc < Nfull;
        alc[nt] = ok ? loadF(al, gc, bf) : 0.f;
        arc[nt] = ok ? loadF(ar, gc, bf) : 0.f;
    }
    for (int mt = 0; mt < 4; ++mt)
        for (int r = 0; r < 4; ++r) {
            float pl = acc[mt][0][r] * alc[0] + acc[mt][1][r] * alc[1];
            float pr = acc[mt][0][r] * arc[0] + acc[mt][1][r] * arc[1];
            for (int off = 1; off < 16; off <<= 1) {
                pl += __shfl_xor(pl, off, 64);
                pr += __shfl_xor(pr, off, 64);
            }
            if (m16 == 0) {
                int gr = row0 + wr + mt * 16 + quad * 4 + r;
                if (gr < M) {
                    if (AMODE == 0) {
                        int hd = col0 / 32 + (wave & 1);
                        el[gr * 8 + hd] = pl;
                        er[gr * 8 + hd] = pr;
                    } else {
                        atomicAdd(&el[gr], pl);
                        atomicAdd(&er[gr], pr);
                    }
                }
            }
        }
}

template <int K_, int AMODE>
__global__ __launch_bounds__(256)
void gemm_attn_k(const unsigned short* __restrict__ A, const unsigned short* __restrict__ Wf,
                 __hip_bfloat16* __restrict__ C, const void* __restrict__ al,
                 const void* __restrict__ ar, const int* __restrict__ flag,
                 float* __restrict__ el, float* __restrict__ er, int M, int Nfull, int Npad) {
    gemm_attn_body<K_, AMODE>(blockIdx.x, blockIdx.y, threadIdx.x,
                              A, Wf, C, al, ar, flag, el, er, M, Nfull, Npad);
}

// ---------- fused: layer-1 GEMM (blocks [0, GB)) + CSR scatter (blocks [GB, GB+SB)) ----------
__global__ __launch_bounds__(256)
void scatter_gemm1_k(const unsigned short* __restrict__ A, const unsigned short* __restrict__ Wf,
                     __hip_bfloat16* __restrict__ C, const void* __restrict__ al,
                     const void* __restrict__ ar, const int* __restrict__ flag,
                     float* __restrict__ el, float* __restrict__ er, int M,
                     const int* __restrict__ src, const int* __restrict__ dst,
                     const int* __restrict__ rowptr, int* __restrict__ cursor,
                     int* __restrict__ ecol, int E, int GB) {
    int b = blockIdx.x, t = threadIdx.x;
    if (b < GB) {
        gemm_attn_body<128, 0>(b >> 2, b & 3, t, A, Wf, C, al, ar, flag, el, er, M, 256, 256);
    } else {
        int e = (b - GB) * 256 + t;
        if (e < E) {
            int d = dst[e];
            int r = atomicSub(&cursor[d], 1);
            ecol[rowptr[d] + r - 1] = src[e];
        }
    }
}

// ---------- single-pass half-wave aggregation (H=8, F=32), unrolled x4 ----------
// optional zelo/zero: zeroed per node (prepares output-layer atomics)
__global__ __launch_bounds__(256)
void aggr1_k(const int* __restrict__ rowptr, const int* __restrict__ ecol,
             const float* __restrict__ el, const float* __restrict__ er,
             const __hip_bfloat16* __restrict__ Hp, __hip_bfloat16* __restrict__ out,
             float* __restrict__ zelo, float* __restrict__ zero_, int N) {
    int t = threadIdx.x;
    int hw = t >> 5, l = t & 31;
    int n = blockIdx.x * 8 + hw;
    if (n >= N) return;
    int beg = rowptr[n], deg = rowptr[n + 1] - beg;

    if (zelo && l == 0) { zelo[n] = 0.f; zero_[n] = 0.f; }

    int hh = l >> 2;
    float er_hh = er[n * 8 + hh];
    float ss = 0.f;
    float acc[8] = {0.f, 0.f, 0.f, 0.f, 0.f, 0.f, 0.f, 0.f};
    const unsigned short* hp = (const unsigned short*)Hp;

    int i = 0;
    for (; i + 4 <= deg; i += 4) {
        int s0 = ecol[beg + i], s1 = ecol[beg + i + 1];
        int s2 = ecol[beg + i + 2], s3 = ecol[beg + i + 3];
        uint4 r0 = *(const uint4*)(hp + (size_t)s0 * 256 + l * 8);
        uint4 r1 = *(const uint4*)(hp + (size_t)s1 * 256 + l * 8);
        uint4 r2 = *(const uint4*)(hp + (size_t)s2 * 256 + l * 8);
        uint4 r3 = *(const uint4*)(hp + (size_t)s3 * 256 + l * 8);
        float v0 = el[s0 * 8 + hh] + er_hh;
        float v1 = el[s1 * 8 + hh] + er_hh;
        float v2 = el[s2 * 8 + hh] + er_hh;
        float v3 = el[s3 * 8 + hh] + er_hh;
        v0 = (v0 >= 0.f) ? v0 : 0.2f * v0;
        v1 = (v1 >= 0.f) ? v1 : 0.2f * v1;
        v2 = (v2 >= 0.f) ? v2 : 0.2f * v2;
        v3 = (v3 >= 0.f) ? v3 : 0.2f * v3;
        float e0 = __expf(v0), e1 = __expf(v1), e2 = __expf(v2), e3 = __expf(v3);
        ss += (e0 + e1) + (e2 + e3);
        unsigned short u0[8], u1[8], u2[8], u3[8];
        *(uint4*)u0 = r0;
        *(uint4*)u1 = r1;
        *(uint4*)u2 = r2;
        *(uint4*)u3 = r3;
        for (int j = 0; j < 8; ++j)
            acc[j] += (e0 * bfbits2f(u0[j]) + e1 * bfbits2f(u1[j])) +
                      (e2 * bfbits2f(u2[j]) + e3 * bfbits2f(u3[j]));
    }
    for (; i < deg; ++i) {
        int s0 = ecol[beg + i];
        uint4 r0 = *(const uint4*)(hp + (size_t)s0 * 256 + l * 8);
        float v0 = el[s0 * 8 + hh] + er_hh;
        v0 = (v0 >= 0.f) ? v0 : 0.2f * v0;
        float e0 = __expf(v0);
        ss += e0;
        unsigned short u0[8];
        *(uint4*)u0 = r0;
        for (int j = 0; j < 8; ++j) acc[j] += e0 * bfbits2f(u0[j]);
    }

    float inv = 1.f / (ss + 1e-16f);
    unsigned short o[8];
    for (int j = 0; j < 8; ++j) {
        float vv = acc[j] * inv;
        vv = (vv > 0.f) ? vv : expm1f(vv);   // ELU
        o[j] = f2bfbits(vv);
    }
    *(uint4*)((unsigned short*)out + (size_t)n * 256 + l * 8) = *(uint4*)o;
}

// ---------- output layer: 8-way vectorized aggregation (stride-64 Hp) + log_softmax ----------
__global__ __launch_bounds__(64)
void aggr_out_k(const int* __restrict__ rowptr, const int* __restrict__ ecol,
                const float* __restrict__ elo, const float* __restrict__ ero,
                const unsigned short* __restrict__ Hp64, void* __restrict__ outp,
                const int* __restrict__ flag, int N) {
    int n = blockIdx.x, l = threadIdx.x;
    int g = l >> 3, f = l & 7;
    int beg = rowptr[n], deg = rowptr[n + 1] - beg;
    float ero_n = ero[n];
    float ss = 0.f;
    float acc[8] = {0.f, 0.f, 0.f, 0.f, 0.f, 0.f, 0.f, 0.f};
    for (int i = g; i < deg; i += 8) {
        int s = ecol[beg + i];
        float v = elo[s] + ero_n;
        v = (v >= 0.f) ? v : 0.2f * v;
        float ex = __expf(v);
        ss += ex;
        uint4 r = *(const uint4*)(Hp64 + (size_t)s * 64 + f * 8);
        unsigned short u[8];
        *(uint4*)u = r;
        for (int j = 0; j < 8; ++j) acc[j] += ex * bfbits2f(u[j]);
    }
    for (int off = 8; off <= 32; off <<= 1) {
        ss += __shfl_xor(ss, off, 64);
        for (int j = 0; j < 8; ++j) acc[j] += __shfl_xor(acc[j], off, 64);
    }
    float inv = 1.f / (ss + 1e-16f);
    float r8[8];
    float vmax = -1e30f;
    for (int j = 0; j < 8; ++j) {
        r8[j] = acc[j] * inv;
        if (f < 5) vmax = fmaxf(vmax, r8[j]);
    }
    for (int off = 1; off <= 4; off <<= 1) vmax = fmaxf(vmax, __shfl_xor(vmax, off, 64));
    float es = 0.f;
    if (f < 5)
        for (int j = 0; j < 8; ++j) es += __expf(r8[j] - vmax);
    for (int off = 1; off <= 4; off <<= 1) es += __shfl_xor(es, off, 64);
    float lse = vmax + logf(es);
    if (f < 5 && g == 0) {
        if (*flag) {
            unsigned short o[8];
            for (int j = 0; j < 8; ++j) o[j] = f2bfbits(r8[j] - lse);
            *(uint4*)((unsigned short*)outp + (size_t)n * 40 + f * 8) = *(uint4*)o;
        } else {
            float* fo = (float*)outp + (size_t)n * 40 + f * 8;
            for (int j = 0; j < 8; ++j) fo[j] = r8[j] - lse;
        }
    }
}

extern "C" void kernel_launch(void* const* d_in, const int* in_sizes, int n_in,
                              void* d_out, int out_size, void* d_ws, size_t ws_size,
                              hipStream_t stream) {
    const int N = N_NODES, E = N_EDGES;
    const void* x   = d_in[0];
    const int* src  = (const int*)d_in[1];
    const int* dst  = (const int*)d_in[2];
    const void* W1  = d_in[3];
    const void* al1 = d_in[4];
    const void* ar1 = d_in[5];
    const void* W2  = d_in[6];
    const void* al2 = d_in[7];
    const void* ar2 = d_in[8];
    const void* Wo  = d_in[9];
    const void* alo = d_in[10];
    const void* aro = d_in[11];

    // workspace (~58.6 MB)
    char* w = (char*)d_ws;
    auto alloc = [&](size_t bytes) { void* p = (void*)w; w += (bytes + 255) & ~(size_t)255; return p; };
    int* flag      = (int*)alloc(4);
    int* rowptr    = (int*)alloc((size_t)(N + 1) * 4);
    int* cursor    = (int*)alloc((size_t)N * 4);
    float* elo     = (float*)alloc((size_t)N * 4);
    float* ero     = (float*)alloc((size_t)N * 4);
    int* ecol      = (int*)alloc((size_t)E * 4);
    float* el      = (float*)alloc((size_t)N * 8 * 4);
    float* er      = (float*)alloc((size_t)N * 8 * 4);
    unsigned short* W1f = (unsigned short*)alloc((size_t)128 * 256 * 2);
    unsigned short* W2f = (unsigned short*)alloc((size_t)256 * 256 * 2);
    unsigned short* Wof = (unsigned short*)alloc((size_t)256 * 64 * 2);
    __hip_bfloat16* Hp   = (__hip_bfloat16*)alloc((size_t)N * 256 * 2);
    __hip_bfloat16* Hagg = (__hip_bfloat16*)alloc((size_t)N * 256 * 2);
    unsigned short* Xb = (unsigned short*)Hagg;   // alias: dead after layer-1 gemm

    int NB = (N + 255) / 256;          // 196
    int MB = (N + 127) / 128;          // 391
    int AB = (N + 7) / 8;
    int GB = MB * 4;                   // gemm1 blocks (flattened 2D)
    int SB = (E + 255) / 256;          // scatter blocks
    int CVT_THREADS = 800000 + 14336 + E;

    // 1: zero cursor (histogram base)
    hipMemsetAsync(cursor, 0, (size_t)N * 4, stream);
    // 2: conversions + histogram
    cvt_hist_k<<<(CVT_THREADS + 255) / 256, 256, 0, stream>>>(
        x, W1, W2, Wo, Xb, W1f, W2f, Wof, flag, dst, cursor);
    // 3: full prefix scan (sync-free)
    scanall_k<<<NB, 256, 0, stream>>>(cursor, rowptr, N, E);
    // 4: layer-1 GEMM + CSR scatter (independent, co-scheduled)
    scatter_gemm1_k<<<GB + SB, 256, 0, stream>>>(
        Xb, W1f, Hp, al1, ar1, flag, el, er, N, src, dst, rowptr, cursor, ecol, E, GB);
    // 5: layer-1 aggregation
    aggr1_k<<<AB, 256, 0, stream>>>(rowptr, ecol, el, er, Hp, Hagg, nullptr, nullptr, N);
    // 6: layer-2 GEMM
    gemm_attn_k<256, 0><<<dim3(MB, 4), 256, 0, stream>>>((const unsigned short*)Hagg, W2f, Hp, al2, ar2, flag, el, er, N, 256, 256);
    // 7: layer-2 aggregation (+ zero elo/ero for the output layer's atomics)
    aggr1_k<<<AB, 256, 0, stream>>>(rowptr, ecol, el, er, Hp, Hagg, elo, ero, N);
    // 8: output GEMM (C stride 64 incl. zero pad; atomic el/er partials)
    gemm_attn_k<256, 1><<<dim3(MB, 1), 256, 0, stream>>>((const unsigned short*)Hagg, Wof, Hp, alo, aro, flag, elo, ero, N, 40, 64);
    // 9: output aggregation + log_softmax
    aggr_out_k<<<N, 64, 0, stream>>>(rowptr, ecol, elo, ero, (const unsigned short*)Hp, d_out, flag, N);
}

// Round 15
// 389.771 us; speedup vs baseline: 1.8064x; 1.1326x over previous
//
#include <hip/hip_runtime.h>
#include <hip/hip_bf16.h>

#define N_NODES 50000
#define N_EDGES 800000

typedef __bf16 bf16x8 __attribute__((ext_vector_type(8)));
typedef float f32x4 __attribute__((ext_vector_type(4)));
typedef float f32x2 __attribute__((ext_vector_type(2)));

__device__ __forceinline__ float loadF(const void* p, size_t i, bool isbf) {
    return isbf ? __bfloat162float(((const __hip_bfloat16*)p)[i]) : ((const float*)p)[i];
}
__device__ __forceinline__ float bfbits2f(unsigned short u) {
    return __uint_as_float(((unsigned)u) << 16);
}
__device__ __forceinline__ unsigned short f2bfbits(float f) {
    __hip_bfloat16 h = __float2bfloat16(f);
    return *(unsigned short*)&h;
}
// fp8 e4m3 (OCP) pack/unpack via gfx950 HW converts
__device__ __forceinline__ unsigned char q_fp8(float v) {
    int p = __builtin_amdgcn_cvt_pk_fp8_f32(v, v, 0, false);
    return (unsigned char)(p & 0xff);
}
__device__ __forceinline__ void acc8_fp8(float ex, uint2 r, float* acc) {
    f32x2 p0 = __builtin_amdgcn_cvt_pk_f32_fp8(r.x, false);
    f32x2 p1 = __builtin_amdgcn_cvt_pk_f32_fp8(r.x, true);
    f32x2 p2 = __builtin_amdgcn_cvt_pk_f32_fp8(r.y, false);
    f32x2 p3 = __builtin_amdgcn_cvt_pk_f32_fp8(r.y, true);
    acc[0] += ex * p0.x; acc[1] += ex * p0.y;
    acc[2] += ex * p1.x; acc[3] += ex * p1.y;
    acc[4] += ex * p2.x; acc[5] += ex * p2.y;
    acc[6] += ex * p3.x; acc[7] += ex * p3.y;
}

// ---------- convert + histogram (independent work fused; per-block dtype detect) ----------
__global__ void cvt_hist_k(const void* __restrict__ x, const void* __restrict__ W1,
                           const void* __restrict__ W2, const void* __restrict__ Wo,
                           unsigned short* __restrict__ Xb, unsigned short* __restrict__ W1f,
                           unsigned short* __restrict__ W2f, unsigned short* __restrict__ Wof,
                           int* __restrict__ flag, const int* __restrict__ dst,
                           int* __restrict__ cursor) {
    __shared__ int s_flag;
    int t = threadIdx.x;
    if (t < 64) {
        const unsigned short* xw = (const unsigned short*)x;
        int cnt = 0;
        for (int i = t; i < 512; i += 64) {
            unsigned e = (xw[2 * i] >> 7) & 0xFFu;
            if (e >= 117u && e <= 134u) cnt++;
        }
        for (int off = 32; off; off >>= 1) cnt += __shfl_down(cnt, off, 64);
        if (t == 0) s_flag = (cnt >= 256) ? 1 : 0;
    }
    __syncthreads();
    bool bf = (s_flag != 0);
    int i = blockIdx.x * blockDim.x + t;
    if (i == 0) *flag = s_flag ? 1 : 0;
    if (i < 800000) {
        if (bf) {
            ((uint4*)Xb)[i] = ((const uint4*)x)[i];
        } else {
            const float* f = (const float*)x + (size_t)i * 8;
            unsigned short r[8];
            for (int j = 0; j < 8; ++j) r[j] = f2bfbits(f[j]);
            *(uint4*)(Xb + (size_t)i * 8) = *(uint4*)r;
        }
        return;
    }
    int u = i - 800000;
    if (u >= 14336) {
        int e = u - 14336;
        if (e < N_EDGES) atomicAdd(&cursor[dst[e]], 1);
        return;
    }
    const void* W; unsigned short* dstp; int Nf, Npad, s, rem;
    if (u < 4096)        { W = W1; dstp = W1f; Nf = 256; Npad = 256; s = u / 1024; rem = u % 1024; }
    else if (u < 12288)  { u -= 4096;  W = W2; dstp = W2f; Nf = 256; Npad = 256; s = u / 1024; rem = u % 1024; }
    else                 { u -= 12288; W = Wo; dstp = Wof; Nf = 40;  Npad = 64;  s = u / 256;  rem = u % 256; }
    int n = rem >> 2, quad = rem & 3;
    unsigned short r[8];
    for (int j = 0; j < 8; ++j) {
        int k = s * 32 + quad * 8 + j;
        r[j] = (n < Nf) ? f2bfbits(loadF(W, (size_t)k * Nf + n, bf)) : (unsigned short)0;
    }
    int uo = (s * Npad + n) * 4 + quad;
    *(uint4*)(dstp + (size_t)uo * 8) = *(uint4*)r;
}

// ---------- sync-free full scan ----------
__global__ __launch_bounds__(256)
void scanall_k(const int* __restrict__ deg, int* __restrict__ rowptr, int N, int E) {
    __shared__ int s[256];
    __shared__ int ws[4];
    __shared__ int s_off;
    int t = threadIdx.x, b = blockIdx.x;
    int base = b * 256;
    int acc = 0;
    for (int i = t; i < base; i += 256) acc += deg[i];
    int wave = t >> 6, lane = t & 63;
    for (int off = 32; off; off >>= 1) acc += __shfl_down(acc, off, 64);
    if (lane == 0) ws[wave] = acc;
    __syncthreads();
    if (t == 0) s_off = ws[0] + ws[1] + ws[2] + ws[3];
    __syncthreads();
    int g = base + t;
    int v = (g < N) ? deg[g] : 0;
    s[t] = v; __syncthreads();
    for (int off = 1; off < 256; off <<= 1) {
        int x = (t >= off) ? s[t - off] : 0;
        __syncthreads();
        s[t] += x;
        __syncthreads();
    }
    if (g < N) rowptr[g] = s_off + s[t] - v;
    if (b == 0 && t == 0) rowptr[N] = E;
}

// ---------- LDS-free MFMA GEMM + fused attention coefficients (device body) ----------
// AMODE 0: C stored fp8 e4m3, stride 256; el/er direct per head.
// AMODE 1: C stored bf16, stride Npad(64) incl. zero pad; el/er atomicAdd.
template <int K_, int AMODE>
__device__ __forceinline__
void gemm_attn_body(int bx, int by, int t,
                    const unsigned short* __restrict__ A, const unsigned short* __restrict__ Wf,
                    void* __restrict__ Cout, const void* __restrict__ al,
                    const void* __restrict__ ar, const int* __restrict__ flag,
                    float* __restrict__ el, float* __restrict__ er, int M, int Nfull, int Npad) {
    int row0 = bx * 128, col0 = by * 64;
    int wave = t >> 6, lane = t & 63;
    int wr = (wave >> 1) * 64, wc = (wave & 1) * 32;
    int m16 = lane & 15, quad = lane >> 4;

    const unsigned short* arow[4];
    for (int mt = 0; mt < 4; ++mt) {
        int gr = row0 + wr + mt * 16 + m16;
        int grc = (gr < M) ? gr : (M - 1);
        arow[mt] = A + (size_t)grc * K_ + quad * 8;
    }
    const unsigned short* bbase[2];
    for (int nt = 0; nt < 2; ++nt) {
        int gc = col0 + wc + nt * 16 + m16;
        bbase[nt] = Wf + ((size_t)(gc * 4 + quad) << 3);
    }

    f32x4 acc[4][2] = {};
#pragma unroll
    for (int s = 0; s < K_ / 32; ++s) {
        bf16x8 a[4], b[2];
        for (int mt = 0; mt < 4; ++mt)
            a[mt] = *(const bf16x8*)(arow[mt] + s * 32);
        for (int nt = 0; nt < 2; ++nt)
            b[nt] = *(const bf16x8*)(bbase[nt] + (size_t)s * Npad * 32);
        for (int mt = 0; mt < 4; ++mt)
            for (int nt = 0; nt < 2; ++nt)
                acc[mt][nt] = __builtin_amdgcn_mfma_f32_16x16x32_bf16(
                    a[mt], b[nt], acc[mt][nt], 0, 0, 0);
    }

    if (AMODE == 0) {
        unsigned char* C8 = (unsigned char*)Cout;
        for (int mt = 0; mt < 4; ++mt)
            for (int nt = 0; nt < 2; ++nt)
                for (int r = 0; r < 4; ++r) {
                    int gr = row0 + wr + mt * 16 + quad * 4 + r;
                    int gc = col0 + wc + nt * 16 + m16;
                    if (gr < M)
                        C8[(size_t)gr * 256 + gc] = q_fp8(acc[mt][nt][r]);
                }
    } else {
        __hip_bfloat16* C = (__hip_bfloat16*)Cout;
        for (int mt = 0; mt < 4; ++mt)
            for (int nt = 0; nt < 2; ++nt)
                for (int r = 0; r < 4; ++r) {
                    int gr = row0 + wr + mt * 16 + quad * 4 + r;
                    int gc = col0 + wc + nt * 16 + m16;
                    if (gr < M && gc < Npad)
                        C[(size_t)gr * Npad + gc] = __float2bfloat16(acc[mt][nt][r]);
                }
    }

    bool bf = (*flag != 0);
    float alc[2], arc[2];
    for (int nt = 0; nt < 2; ++nt) {
        int gc = col0 + wc + nt * 16 + m16;
        bool ok = gc < Nfull;
        alc[nt] = ok ? loadF(al, gc, bf) : 0.f;
        arc[nt] = ok ? loadF(ar, gc, bf) : 0.f;
    }
    for (int mt = 0; mt < 4; ++mt)
        for (int r = 0; r < 4; ++r) {
            float pl = acc[mt][0][r] * alc[0] + acc[mt][1][r] * alc[1];
            float pr = acc[mt][0][r] * arc[0] + acc[mt][1][r] * arc[1];
            for (int off = 1; off < 16; off <<= 1) {
                pl += __shfl_xor(pl, off, 64);
                pr += __shfl_xor(pr, off, 64);
            }
            if (m16 == 0) {
                int gr = row0 + wr + mt * 16 + quad * 4 + r;
                if (gr < M) {
                    if (AMODE == 0) {
                        int hd = col0 / 32 + (wave & 1);
                        el[gr * 8 + hd] = pl;
                        er[gr * 8 + hd] = pr;
                    } else {
                        atomicAdd(&el[gr], pl);
                        atomicAdd(&er[gr], pr);
                    }
                }
            }
        }
}

template <int K_, int AMODE>
__global__ __launch_bounds__(256)
void gemm_attn_k(const unsigned short* __restrict__ A, const unsigned short* __restrict__ Wf,
                 void* __restrict__ Cout, const void* __restrict__ al,
                 const void* __restrict__ ar, const int* __restrict__ flag,
                 float* __restrict__ el, float* __restrict__ er, int M, int Nfull, int Npad) {
    gemm_attn_body<K_, AMODE>(blockIdx.x, blockIdx.y, threadIdx.x,
                              A, Wf, Cout, al, ar, flag, el, er, M, Nfull, Npad);
}

// ---------- fused: layer-1 GEMM (blocks [0, GB)) + CSR scatter (blocks [GB, GB+SB)) ----------
__global__ __launch_bounds__(256)
void scatter_gemm1_k(const unsigned short* __restrict__ A, const unsigned short* __restrict__ Wf,
                     void* __restrict__ Cout, const void* __restrict__ al,
                     const void* __restrict__ ar, const int* __restrict__ flag,
                     float* __restrict__ el, float* __restrict__ er, int M,
                     const int* __restrict__ src, const int* __restrict__ dst,
                     const int* __restrict__ rowptr, int* __restrict__ cursor,
                     int* __restrict__ ecol, int E, int GB) {
    int b = blockIdx.x, t = threadIdx.x;
    if (b < GB) {
        gemm_attn_body<128, 0>(b >> 2, b & 3, t, A, Wf, Cout, al, ar, flag, el, er, M, 256, 256);
    } else {
        int e = (b - GB) * 256 + t;
        if (e < E) {
            int d = dst[e];
            int r = atomicSub(&cursor[d], 1);
            ecol[rowptr[d] + r - 1] = src[e];
        }
    }
}

// ---------- single-pass half-wave aggregation (H=8, F=32), fp8 gather, unrolled x4 ----------
__global__ __launch_bounds__(256)
void aggr1_k(const int* __restrict__ rowptr, const int* __restrict__ ecol,
             const float* __restrict__ el, const float* __restrict__ er,
             const unsigned char* __restrict__ Hp8, __hip_bfloat16* __restrict__ out,
             float* __restrict__ zelo, float* __restrict__ zero_, int N) {
    int t = threadIdx.x;
    int hw = t >> 5, l = t & 31;
    int n = blockIdx.x * 8 + hw;
    if (n >= N) return;
    int beg = rowptr[n], deg = rowptr[n + 1] - beg;

    if (zelo && l == 0) { zelo[n] = 0.f; zero_[n] = 0.f; }

    int hh = l >> 2;
    float er_hh = er[n * 8 + hh];
    float ss = 0.f;
    float acc[8] = {0.f, 0.f, 0.f, 0.f, 0.f, 0.f, 0.f, 0.f};

    int i = 0;
    for (; i + 4 <= deg; i += 4) {
        int s0 = ecol[beg + i], s1 = ecol[beg + i + 1];
        int s2 = ecol[beg + i + 2], s3 = ecol[beg + i + 3];
        uint2 r0 = *(const uint2*)(Hp8 + (size_t)s0 * 256 + l * 8);
        uint2 r1 = *(const uint2*)(Hp8 + (size_t)s1 * 256 + l * 8);
        uint2 r2 = *(const uint2*)(Hp8 + (size_t)s2 * 256 + l * 8);
        uint2 r3 = *(const uint2*)(Hp8 + (size_t)s3 * 256 + l * 8);
        float v0 = el[s0 * 8 + hh] + er_hh;
        float v1 = el[s1 * 8 + hh] + er_hh;
        float v2 = el[s2 * 8 + hh] + er_hh;
        float v3 = el[s3 * 8 + hh] + er_hh;
        v0 = (v0 >= 0.f) ? v0 : 0.2f * v0;
        v1 = (v1 >= 0.f) ? v1 : 0.2f * v1;
        v2 = (v2 >= 0.f) ? v2 : 0.2f * v2;
        v3 = (v3 >= 0.f) ? v3 : 0.2f * v3;
        float e0 = __expf(v0), e1 = __expf(v1), e2 = __expf(v2), e3 = __expf(v3);
        ss += (e0 + e1) + (e2 + e3);
        acc8_fp8(e0, r0, acc);
        acc8_fp8(e1, r1, acc);
        acc8_fp8(e2, r2, acc);
        acc8_fp8(e3, r3, acc);
    }
    for (; i < deg; ++i) {
        int s0 = ecol[beg + i];
        uint2 r0 = *(const uint2*)(Hp8 + (size_t)s0 * 256 + l * 8);
        float v0 = el[s0 * 8 + hh] + er_hh;
        v0 = (v0 >= 0.f) ? v0 : 0.2f * v0;
        float e0 = __expf(v0);
        ss += e0;
        acc8_fp8(e0, r0, acc);
    }

    float inv = 1.f / (ss + 1e-16f);
    unsigned short o[8];
    for (int j = 0; j < 8; ++j) {
        float vv = acc[j] * inv;
        vv = (vv > 0.f) ? vv : expm1f(vv);   // ELU
        o[j] = f2bfbits(vv);
    }
    *(uint4*)((unsigned short*)out + (size_t)n * 256 + l * 8) = *(uint4*)o;
}

// ---------- output layer: 8-way vectorized aggregation (stride-64 bf16 Hp) + log_softmax ----------
__global__ __launch_bounds__(64)
void aggr_out_k(const int* __restrict__ rowptr, const int* __restrict__ ecol,
                const float* __restrict__ elo, const float* __restrict__ ero,
                const unsigned short* __restrict__ Hp64, void* __restrict__ outp,
                const int* __restrict__ flag, int N) {
    int n = blockIdx.x, l = threadIdx.x;
    int g = l >> 3, f = l & 7;
    int beg = rowptr[n], deg = rowptr[n + 1] - beg;
    float ero_n = ero[n];
    float ss = 0.f;
    float acc[8] = {0.f, 0.f, 0.f, 0.f, 0.f, 0.f, 0.f, 0.f};
    for (int i = g; i < deg; i += 8) {
        int s = ecol[beg + i];
        float v = elo[s] + ero_n;
        v = (v >= 0.f) ? v : 0.2f * v;
        float ex = __expf(v);
        ss += ex;
        uint4 r = *(const uint4*)(Hp64 + (size_t)s * 64 + f * 8);
        unsigned short u[8];
        *(uint4*)u = r;
        for (int j = 0; j < 8; ++j) acc[j] += ex * bfbits2f(u[j]);
    }
    for (int off = 8; off <= 32; off <<= 1) {
        ss += __shfl_xor(ss, off, 64);
        for (int j = 0; j < 8; ++j) acc[j] += __shfl_xor(acc[j], off, 64);
    }
    float inv = 1.f / (ss + 1e-16f);
    float r8[8];
    float vmax = -1e30f;
    for (int j = 0; j < 8; ++j) {
        r8[j] = acc[j] * inv;
        if (f < 5) vmax = fmaxf(vmax, r8[j]);
    }
    for (int off = 1; off <= 4; off <<= 1) vmax = fmaxf(vmax, __shfl_xor(vmax, off, 64));
    float es = 0.f;
    if (f < 5)
        for (int j = 0; j < 8; ++j) es += __expf(r8[j] - vmax);
    for (int off = 1; off <= 4; off <<= 1) es += __shfl_xor(es, off, 64);
    float lse = vmax + logf(es);
    if (f < 5 && g == 0) {
        if (*flag) {
            unsigned short o[8];
            for (int j = 0; j < 8; ++j) o[j] = f2bfbits(r8[j] - lse);
            *(uint4*)((unsigned short*)outp + (size_t)n * 40 + f * 8) = *(uint4*)o;
        } else {
            float* fo = (float*)outp + (size_t)n * 40 + f * 8;
            for (int j = 0; j < 8; ++j) fo[j] = r8[j] - lse;
        }
    }
}

extern "C" void kernel_launch(void* const* d_in, const int* in_sizes, int n_in,
                              void* d_out, int out_size, void* d_ws, size_t ws_size,
                              hipStream_t stream) {
    const int N = N_NODES, E = N_EDGES;
    const void* x   = d_in[0];
    const int* src  = (const int*)d_in[1];
    const int* dst  = (const int*)d_in[2];
    const void* W1  = d_in[3];
    const void* al1 = d_in[4];
    const void* ar1 = d_in[5];
    const void* W2  = d_in[6];
    const void* al2 = d_in[7];
    const void* ar2 = d_in[8];
    const void* Wo  = d_in[9];
    const void* alo = d_in[10];
    const void* aro = d_in[11];

    // workspace (~46 MB)
    char* w = (char*)d_ws;
    auto alloc = [&](size_t bytes) { void* p = (void*)w; w += (bytes + 255) & ~(size_t)255; return p; };
    int* flag      = (int*)alloc(4);
    int* rowptr    = (int*)alloc((size_t)(N + 1) * 4);
    int* cursor    = (int*)alloc((size_t)N * 4);
    float* elo     = (float*)alloc((size_t)N * 4);
    float* ero     = (float*)alloc((size_t)N * 4);
    int* ecol      = (int*)alloc((size_t)E * 4);
    float* el      = (float*)alloc((size_t)N * 8 * 4);
    float* er      = (float*)alloc((size_t)N * 8 * 4);
    unsigned short* W1f = (unsigned short*)alloc((size_t)128 * 256 * 2);
    unsigned short* W2f = (unsigned short*)alloc((size_t)256 * 256 * 2);
    unsigned short* Wof = (unsigned short*)alloc((size_t)256 * 64 * 2);
    // Hp region: fp8 N*256 B for layers 1/2; bf16 N*64*2 B for the output layer (aliased)
    unsigned char* Hp8 = (unsigned char*)alloc((size_t)N * 256);
    __hip_bfloat16* Hagg = (__hip_bfloat16*)alloc((size_t)N * 256 * 2);
    unsigned short* Xb = (unsigned short*)Hagg;   // alias: dead after layer-1 gemm
    unsigned short* Hp64 = (unsigned short*)Hp8;  // alias: output-layer bf16 proj (Hp8 dead)

    int NB = (N + 255) / 256;
    int MB = (N + 127) / 128;
    int AB = (N + 7) / 8;
    int GB = MB * 4;
    int SB = (E + 255) / 256;
    int CVT_THREADS = 800000 + 14336 + E;

    // 1: zero cursor (histogram base)
    hipMemsetAsync(cursor, 0, (size_t)N * 4, stream);
    // 2: conversions + histogram
    cvt_hist_k<<<(CVT_THREADS + 255) / 256, 256, 0, stream>>>(
        x, W1, W2, Wo, Xb, W1f, W2f, Wof, flag, dst, cursor);
    // 3: full prefix scan (sync-free)
    scanall_k<<<NB, 256, 0, stream>>>(cursor, rowptr, N, E);
    // 4: layer-1 GEMM (fp8 out) + CSR scatter
    scatter_gemm1_k<<<GB + SB, 256, 0, stream>>>(
        Xb, W1f, Hp8, al1, ar1, flag, el, er, N, src, dst, rowptr, cursor, ecol, E, GB);
    // 5: layer-1 aggregation (fp8 gather)
    aggr1_k<<<AB, 256, 0, stream>>>(rowptr, ecol, el, er, Hp8, Hagg, nullptr, nullptr, N);
    // 6: layer-2 GEMM (fp8 out)
    gemm_attn_k<256, 0><<<dim3(MB, 4), 256, 0, stream>>>((const unsigned short*)Hagg, W2f, Hp8, al2, ar2, flag, el, er, N, 256, 256);
    // 7: layer-2 aggregation (+ zero elo/ero)
    aggr1_k<<<AB, 256, 0, stream>>>(rowptr, ecol, el, er, Hp8, Hagg, elo, ero, N);
    // 8: output GEMM (bf16 out, stride 64; atomic el/er partials)
    gemm_attn_k<256, 1><<<dim3(MB, 1), 256, 0, stream>>>((const unsigned short*)Hagg, Wof, Hp64, alo, aro, flag, elo, ero, N, 40, 64);
    // 9: output aggregation + log_softmax
    aggr_out_k<<<N, 64, 0, stream>>>(rowptr, ecol, elo, ero, Hp64, d_out, flag, N);
}